// Round 8
// baseline (722.592 us; speedup 1.0000x reference)
//
#include <hip/hip_runtime.h>
#include <stdint.h>

using f16 = _Float16;
typedef __attribute__((ext_vector_type(8))) f16 f16x8;
typedef __attribute__((ext_vector_type(4))) float f32x4;

constexpr int N = 1024;

__device__ __forceinline__ float leaky(float v) { return v >= 0.f ? v : 0.01f * v; }

__device__ __forceinline__ void dma16(const void* g, void* l) {
    __builtin_amdgcn_global_load_lds(
        (const __attribute__((address_space(1))) uint32_t*)g,
        (__attribute__((address_space(3))) uint32_t*)l, 16, 0, 0);
}

// ---------------------------------------------------------------------------
// Unified GEMM for BinaryTreeConv (SEGS=3, gather) and ChannelMixer (SEGS=1,
// identity rows; ISMIX epilogue = fused TreeLayerNorm + leaky, in place).
//
// r7 lessons applied:
//  * persistent-W: one block stages W once, loops TILES n-tiles (amortize)
//  * XCD batch affinity: 1-D grid, p%8 == b%8 -> all blocks of a batch share
//    one XCD's L2; gathered X rows fetched from HBM once
//  * depth-3 register prefetch pipeline on the A-gather loads
// Block: 512 threads = 8 n-waves; per tile 256n x 64o.
// ---------------------------------------------------------------------------
template<int CI, int CO, int SEGS, int NSTG, int TILES, bool ISMIX>
__global__ __launch_bounds__(512) void gemm_kernel(
    const f16* __restrict__ X, const int* __restrict__ idx,
    const f16* __restrict__ Wf, const float* __restrict__ bias,
    f16* __restrict__ Y, float2* __restrict__ part,
    const float2* __restrict__ stats)
{
    constexpr int SKT = SEGS * CI / 32;     // total k-chunks of 32
    constexpr int KS32 = SKT / NSTG;        // k-chunks per staging phase
    constexpr int Ug = CO / 16;             // global o-subtile count
    constexpr int O2 = CO / 64;             // o-blocks per batch
    constexpr int G = (4 / TILES) * O2;     // blocks per batch
    constexpr int NGRAN = KS32 * 256;       // 16B granules per phase
    static_assert(CI % 32 == 0 && SKT % NSTG == 0 && 4 % TILES == 0, "geometry");

    __shared__ alignas(16) f16 lds[KS32 * 2048];   // [skl][uu][l][8]
    __shared__ float redu[16];

    const int tid = threadIdx.x;
    const int w = tid >> 6, l = tid & 63;

    // XCD-affine decode: p % 8 == b % 8
    const int p = blockIdx.x;
    const int q = p >> 3;
    const int b = (p & 7) + 8 * (q / G);
    const int g = q % G;
    const int u0 = (g % O2) * 4;
    const int nbase = (g / O2) * TILES;

    const f16* xb = X + (size_t)b * N * CI;
    const int koff = 8 * (l >> 4);

    auto stageW = [&](int pp) {
        for (int gg = tid; gg < NGRAN; gg += 512) {
            int skk = gg >> 8, uu = (gg >> 6) & 3, ll = gg & 63;
            dma16(Wf + (((size_t)(pp * KS32 + skk) * Ug + u0 + uu) * 64 + ll) * 8,
                  (char*)lds + (size_t)gg * 16);
        }
    };

    if constexpr (NSTG == 1) { stageW(0); __syncthreads(); }

    float ps1 = 0.f, ps2 = 0.f;
    const float2 st = ISMIX ? stats[b] : make_float2(0.f, 0.f);

    #pragma unroll 1
    for (int t = 0; t < TILES; ++t) {
        const int n0 = (nbase + t) * 256;

        int rows[2][SEGS];
        #pragma unroll
        for (int rt = 0; rt < 2; ++rt) {
            int n = n0 + 32 * w + 16 * rt + (l & 15);
            if constexpr (ISMIX) {
                rows[rt][0] = n;
            } else {
                const int* ip = idx + (size_t)b * 3 * N + 3 * n;
                #pragma unroll
                for (int s = 0; s < SEGS; ++s) rows[rt][s] = ip[s];
            }
        }

        auto A0 = [&](int sk) {
            int seg = (sk * 32) / CI;                 // compile-time
            int co = sk * 32 - seg * CI + koff;
            return *(const f16x8*)(xb + (size_t)rows[0][seg] * CI + co);
        };
        auto A1 = [&](int sk) {
            int seg = (sk * 32) / CI;
            int co = sk * 32 - seg * CI + koff;
            return *(const f16x8*)(xb + (size_t)rows[1][seg] * CI + co);
        };

        f32x4 acc[2][4] = {};

        #pragma unroll
        for (int pp = 0; pp < NSTG; ++pp) {
            if constexpr (NSTG > 1) { stageW(pp); __syncthreads(); }

            constexpr int D = KS32 < 3 ? KS32 : 3;    // pipeline depth
            f16x8 pa0[3], pa1[3];
            #pragma unroll
            for (int d = 0; d < D; ++d) { pa0[d] = A0(pp * KS32 + d); pa1[d] = A1(pp * KS32 + d); }

            #pragma unroll
            for (int skl = 0; skl < KS32; ++skl) {
                f16x8 a0 = pa0[skl % 3], a1 = pa1[skl % 3];
                if (skl + 3 < KS32) {
                    pa0[skl % 3] = A0(pp * KS32 + skl + 3);
                    pa1[skl % 3] = A1(pp * KS32 + skl + 3);
                }
                #pragma unroll
                for (int uu = 0; uu < 4; ++uu) {
                    f16x8 wv = *(const f16x8*)(lds + ((size_t)(skl * 4 + uu) * 64 + l) * 8);
                    acc[0][uu] = __builtin_amdgcn_mfma_f32_16x16x32_f16(a0, wv, acc[0][uu], 0, 0, 0);
                    acc[1][uu] = __builtin_amdgcn_mfma_f32_16x16x32_f16(a1, wv, acc[1][uu], 0, 0, 0);
                }
            }
            if constexpr (NSTG > 1) __syncthreads();   // before next stage overwrites
        }

        if constexpr (!ISMIX) {
            #pragma unroll
            for (int rt = 0; rt < 2; ++rt) {
                #pragma unroll
                for (int uu = 0; uu < 4; ++uu) {
                    int o = (u0 + uu) * 16 + (l & 15);
                    float bcv = bias[o];
                    size_t rb = ((size_t)b * N + (n0 + 32 * w + 16 * rt + 4 * (l >> 4))) * CO + o;
                    #pragma unroll
                    for (int j = 0; j < 4; ++j) {
                        float v = acc[rt][uu][j] + bcv;
                        Y[rb + (size_t)j * CO] = (f16)v;
                        ps1 += v; ps2 += v * v;
                    }
                }
            }
        } else {
            #pragma unroll
            for (int rt = 0; rt < 2; ++rt) {
                #pragma unroll
                for (int uu = 0; uu < 4; ++uu) {
                    int o = (u0 + uu) * 16 + (l & 15);
                    float bmv = bias[o];
                    size_t rb = ((size_t)b * N + (n0 + 32 * w + 16 * rt + 4 * (l >> 4))) * CO + o;
                    #pragma unroll
                    for (int j = 0; j < 4; ++j) {
                        size_t off = rb + (size_t)j * CO;
                        float ycv = (float)Y[off];
                        float v = acc[rt][uu][j] + bmv + (ycv - st.x) * st.y;
                        Y[off] = (f16)leaky(v);
                    }
                }
            }
        }
    }

    if constexpr (!ISMIX) {
        #pragma unroll
        for (int m = 32; m; m >>= 1) { ps1 += __shfl_xor(ps1, m); ps2 += __shfl_xor(ps2, m); }
        if (l == 0) { redu[w * 2] = ps1; redu[w * 2 + 1] = ps2; }
        __syncthreads();
        if (tid == 0) {
            float t1 = 0.f, t2 = 0.f;
            #pragma unroll
            for (int k = 0; k < 8; ++k) { t1 += redu[2 * k]; t2 += redu[2 * k + 1]; }
            part[(size_t)b * 16 + g] = make_float2(t1, t2);
        }
    }
}

__global__ __launch_bounds__(64) void reduce_stats_kernel(
    const float2* __restrict__ part, float2* __restrict__ stats, int nparts, float Mf)
{
    int b = blockIdx.x;
    float s1 = 0.f, s2 = 0.f;
    for (int i = threadIdx.x; i < nparts; i += 64) {
        float2 p = part[(size_t)b * 16 + i];
        s1 += p.x; s2 += p.y;
    }
    #pragma unroll
    for (int m = 32; m; m >>= 1) { s1 += __shfl_xor(s1, m); s2 += __shfl_xor(s2, m); }
    if (threadIdx.x == 0) {
        float mu = s1 / Mf;
        float var = (s2 - s1 * s1 / Mf) / (Mf - 1.f);   // ddof = 1
        var = fmaxf(var, 0.f);
        stats[b] = make_float2(mu, 1.f / (sqrtf(var) + 1e-5f));
    }
}

// fp32 [B][160][N] -> f16 [B][N][160]
__global__ __launch_bounds__(256) void transpose_kernel(
    const float* __restrict__ trees, f16* __restrict__ X0)
{
    __shared__ f16 tile[32][66];
    int b = blockIdx.z, c0 = blockIdx.y * 32, n0 = blockIdx.x * 64;
    int tid = threadIdx.x;
    int nl = tid & 63, c4 = tid >> 6;
    #pragma unroll
    for (int cc = 0; cc < 8; ++cc) {
        int c = c4 * 8 + cc;
        tile[c][nl] = (f16)trees[((size_t)b * 160 + c0 + c) * N + n0 + nl];
    }
    __syncthreads();
    int nn = tid >> 2, gc = tid & 3;
    f16x8 pack;
    #pragma unroll
    for (int e = 0; e < 8; ++e) pack[e] = tile[gc * 8 + e][nn];
    *(f16x8*)(X0 + ((size_t)b * N + n0 + nn) * 160 + c0 + gc * 8) = pack;
}

// weights -> fragment-ready f16 layout: elem ((skk*U+u)*64+l)*8+j  holds
// W[kap = 32*skk+8*(l>>4)+j][o = 16u+(l&15)], kappa-order kap = k*CI + c.
__global__ __launch_bounds__(256) void prepW_kernel(
    const float* __restrict__ Wsrc, f16* __restrict__ out,
    int K, int CO, int CI, int isconv)
{
    int e = blockIdx.x * 256 + threadIdx.x;
    if (e >= K * CO) return;
    int j = e & 7, l = (e >> 3) & 63, r = e >> 9;
    int U = CO / 16;
    int u = r % U, t = r / U;
    int kap = 32 * t + 8 * (l >> 4) + j;
    int o = 16 * u + (l & 15);
    float v = isconv ? Wsrc[((size_t)o * CI + (kap % CI)) * 3 + kap / CI]
                     : Wsrc[(size_t)o * CI + kap];
    out[e] = (f16)v;
}

// masked max-pool over valid nodes + 64->32->1 MLP; x3 is [b][n][64] f16.
__global__ __launch_bounds__(256) void final_kernel(
    const f16* __restrict__ x3, const int* __restrict__ nodes,
    const float* __restrict__ W1, const float* __restrict__ b1,
    const float* __restrict__ W2, const float* __restrict__ b2,
    float* __restrict__ out)
{
    int b = blockIdx.x, tid = threadIdx.x;
    int o = tid & 63, r = tid >> 6;
    int nv = nodes[b];
    const f16* p = x3 + (size_t)b * N * 64 + o;
    float mx = -3.4e38f;
    for (int n = r; n < nv; n += 4) mx = fmaxf(mx, (float)p[(size_t)n * 64]);
    __shared__ float pool[4][64];
    __shared__ float pooled[64], hbuf[32];
    pool[r][o] = mx;
    __syncthreads();
    if (tid < 64) pooled[tid] = fmaxf(fmaxf(pool[0][tid], pool[1][tid]),
                                      fmaxf(pool[2][tid], pool[3][tid]));
    __syncthreads();
    if (tid < 32) {
        float h = b1[tid];
        #pragma unroll 8
        for (int oo = 0; oo < 64; ++oo) h += pooled[oo] * W1[oo * 32 + tid];
        hbuf[tid] = leaky(h);
    }
    __syncthreads();
    if (tid == 0) {
        float rr = b2[0];
        for (int jj = 0; jj < 32; ++jj) rr += hbuf[jj] * W2[jj];
        out[b] = rr;
    }
}

extern "C" void kernel_launch(void* const* d_in, const int* in_sizes, int n_in,
                              void* d_out, int out_size, void* d_ws, size_t ws_size,
                              hipStream_t stream)
{
    (void)in_sizes; (void)n_in; (void)out_size; (void)ws_size;
    const float* trees = (const float*)d_in[0];
    const int* indexes = (const int*)d_in[1];
    const int* nodes   = (const int*)d_in[2];
    const float* Wc1 = (const float*)d_in[3];
    const float* bc1 = (const float*)d_in[4];
    const float* Wm1 = (const float*)d_in[5];
    const float* bm1 = (const float*)d_in[6];
    const float* Wc2 = (const float*)d_in[7];
    const float* bc2 = (const float*)d_in[8];
    const float* Wm2 = (const float*)d_in[9];
    const float* bm2 = (const float*)d_in[10];
    const float* Wc3 = (const float*)d_in[11];
    const float* bc3 = (const float*)d_in[12];
    const float* Wm3 = (const float*)d_in[13];
    const float* bm3 = (const float*)d_in[14];
    const float* W1 = (const float*)d_in[15];
    const float* b1 = (const float*)d_in[16];
    const float* W2 = (const float*)d_in[17];
    const float* b2 = (const float*)d_in[18];
    float* out = (float*)d_out;

    // ws layout:
    //   [0, 83886080)            X0 [B][N][160] f16      -> later yc2/x2 (67MB)
    //   [83886080, 218103808)    yc1/x1 [B][N][256] f16  -> later yc3/x3 (33.5MB)
    //   [218103808, ...)         Wfrags, parts, stats
    char* ws = (char*)d_ws;
    f16* X0 = (f16*)ws;
    f16* A1 = (f16*)(ws + 83886080);
    f16* A2 = (f16*)ws;
    f16* A3 = A1;
    size_t toff = 218103808;
    f16* Wfc1 = (f16*)(ws + toff); toff += (size_t)480 * 256 * 2;
    f16* Wfm1 = (f16*)(ws + toff); toff += (size_t)160 * 256 * 2;
    f16* Wfc2 = (f16*)(ws + toff); toff += (size_t)768 * 128 * 2;
    f16* Wfm2 = (f16*)(ws + toff); toff += (size_t)256 * 128 * 2;
    f16* Wfc3 = (f16*)(ws + toff); toff += (size_t)384 * 64 * 2;
    f16* Wfm3 = (f16*)(ws + toff); toff += (size_t)128 * 64 * 2;
    float2* part  = (float2*)(ws + toff); toff += (size_t)256 * 16 * 8;
    float2* stats = (float2*)(ws + toff);

    transpose_kernel<<<dim3(16, 5, 256), 256, 0, stream>>>(trees, X0);
    prepW_kernel<<<480 * 256 / 256, 256, 0, stream>>>(Wc1, Wfc1, 480, 256, 160, 1);
    prepW_kernel<<<160 * 256 / 256, 256, 0, stream>>>(Wm1, Wfm1, 160, 256, 160, 0);
    prepW_kernel<<<768 * 128 / 256, 256, 0, stream>>>(Wc2, Wfc2, 768, 128, 256, 1);
    prepW_kernel<<<256 * 128 / 256, 256, 0, stream>>>(Wm2, Wfm2, 256, 128, 256, 0);
    prepW_kernel<<<384 * 64 / 256, 256, 0, stream>>>(Wc3, Wfc3, 384, 64, 128, 1);
    prepW_kernel<<<128 * 64 / 256, 256, 0, stream>>>(Wm3, Wfm3, 128, 64, 128, 0);

    // layer 1: CI=160, CO=256  (G=4 -> 1024 blocks)
    gemm_kernel<160, 256, 3, 1, 4, false><<<1024, 512, 0, stream>>>(
        X0, indexes, Wfc1, bc1, A1, part, nullptr);
    reduce_stats_kernel<<<256, 64, 0, stream>>>(part, stats, 4, 262144.f);
    gemm_kernel<160, 256, 1, 1, 4, true><<<1024, 512, 0, stream>>>(
        X0, nullptr, Wfm1, bm1, A1, nullptr, stats);

    // layer 2: CI=256, CO=128  (conv: W=96KB -> NSTG=2, TILES=1, G=8 -> 2048)
    gemm_kernel<256, 128, 3, 2, 1, false><<<2048, 512, 0, stream>>>(
        A1, indexes, Wfc2, bc2, A2, part, nullptr);
    reduce_stats_kernel<<<256, 64, 0, stream>>>(part, stats, 8, 131072.f);
    gemm_kernel<256, 128, 1, 1, 4, true><<<512, 512, 0, stream>>>(
        A1, nullptr, Wfm2, bm2, A2, nullptr, stats);

    // layer 3: CI=128, CO=64  (conv: TILES=2, G=2 -> 512; mix: TILES=1, G=4 -> 1024)
    gemm_kernel<128, 64, 3, 1, 2, false><<<512, 512, 0, stream>>>(
        A2, indexes, Wfc3, bc3, A3, part, nullptr);
    reduce_stats_kernel<<<256, 64, 0, stream>>>(part, stats, 2, 65536.f);
    gemm_kernel<128, 64, 1, 1, 1, true><<<1024, 512, 0, stream>>>(
        A2, nullptr, Wfm3, bm3, A3, nullptr, stats);

    final_kernel<<<256, 256, 0, stream>>>(A3, nodes, W1, b1, W2, b2, out);
}